// Round 5
// baseline (248.813 us; speedup 1.0000x reference)
//
#include <hip/hip_runtime.h>
#include <hip/hip_bf16.h>

typedef float f32x16 __attribute__((ext_vector_type(16)));
typedef int   i32x8  __attribute__((ext_vector_type(8)));
typedef int   i32x4  __attribute__((ext_vector_type(4)));

#define FP8_MAX 448.0f

// ---------------- helpers ----------------

__device__ __forceinline__ void g2l16(const void* g, void* l) {
    __builtin_amdgcn_global_load_lds(
        (const __attribute__((address_space(1))) void*)g,
        (__attribute__((address_space(3))) void*)l,
        16, 0, 0);
}

__device__ __forceinline__ float scale_from(float amax) {
    float s = FP8_MAX / (amax * 1.1f);
    return (amax == 0.0f) ? 1.0f : fminf(s, 10000.0f);
}

// ---------------- preprocessing (unchanged, verified rounds 3-4) ----------------

__global__ void init_kernel(unsigned* amax) {
    amax[0] = 0u;
    amax[1] = 0u;
}

__global__ void amax_fused_kernel(const float* __restrict__ x, size_t nx,
                                  const float* __restrict__ w, size_t nw,
                                  unsigned* __restrict__ amax, int xblocks) {
    const float* src;
    size_t n;
    unsigned* out;
    int bid, nb;
    if ((int)blockIdx.x < xblocks) {
        src = x; n = nx; out = amax; bid = blockIdx.x; nb = xblocks;
    } else {
        src = w; n = nw; out = amax + 1; bid = blockIdx.x - xblocks; nb = gridDim.x - xblocks;
    }
    float m = 0.0f;
    const size_t ustep = (size_t)blockDim.x * 4;
    const size_t chunkf = ustep * 8;
    size_t base = (size_t)bid * chunkf + (size_t)threadIdx.x * 4;
    const size_t gstride = (size_t)nb * chunkf;
    for (; base < n; base += gstride) {
        float4 v[8];
        #pragma unroll
        for (int u = 0; u < 8; ++u) {
            size_t idx = base + (size_t)u * ustep;
            float4 vv = {0.0f, 0.0f, 0.0f, 0.0f};
            if (idx < n) vv = *(const float4*)(src + idx);
            v[u] = vv;
        }
        #pragma unroll
        for (int u = 0; u < 8; ++u)
            m = fmaxf(m, fmaxf(fmaxf(fabsf(v[u].x), fabsf(v[u].y)),
                               fmaxf(fabsf(v[u].z), fabsf(v[u].w))));
    }
    #pragma unroll
    for (int off = 32; off > 0; off >>= 1)
        m = fmaxf(m, __shfl_xor(m, off));
    __shared__ float sm[4];
    if ((threadIdx.x & 63) == 0) sm[threadIdx.x >> 6] = m;
    __syncthreads();
    if (threadIdx.x == 0) {
        float mm = fmaxf(fmaxf(sm[0], sm[1]), fmaxf(sm[2], sm[3]));
        atomicMax(out, __float_as_uint(mm));
    }
}

__device__ __forceinline__ float qclamp(float v, float s) {
    return fminf(fmaxf(v * s, -FP8_MAX), FP8_MAX);
}

__global__ void quant_fused_kernel(const float* __restrict__ x, size_t nx,
                                   const float* __restrict__ w, size_t nw,
                                   const unsigned* __restrict__ amax,
                                   unsigned char* __restrict__ xq,
                                   unsigned char* __restrict__ wq, int xblocks) {
    const float* src;
    size_t n;
    unsigned char* dst;
    int bid, nb, sel;
    if ((int)blockIdx.x < xblocks) {
        src = x; n = nx; dst = xq; bid = blockIdx.x; nb = xblocks; sel = 0;
    } else {
        src = w; n = nw; dst = wq; bid = blockIdx.x - xblocks; nb = gridDim.x - xblocks; sel = 1;
    }
    const float s = scale_from(__uint_as_float(amax[sel]));
    const size_t ustep = (size_t)blockDim.x * 4;
    const size_t chunkf = ustep * 4;
    size_t base = (size_t)bid * chunkf + (size_t)threadIdx.x * 4;
    const size_t gstride = (size_t)nb * chunkf;
    for (; base < n; base += gstride) {
        float4 v[4];
        bool ok[4];
        #pragma unroll
        for (int u = 0; u < 4; ++u) {
            size_t idx = base + (size_t)u * ustep;
            ok[u] = idx < n;
            float4 vv = {0.0f, 0.0f, 0.0f, 0.0f};
            if (ok[u]) vv = *(const float4*)(src + idx);
            v[u] = vv;
        }
        #pragma unroll
        for (int u = 0; u < 4; ++u) {
            if (ok[u]) {
                int p = __builtin_amdgcn_cvt_pk_fp8_f32(qclamp(v[u].x, s), qclamp(v[u].y, s), 0, false);
                p = __builtin_amdgcn_cvt_pk_fp8_f32(qclamp(v[u].z, s), qclamp(v[u].w, s), p, true);
                *(unsigned*)(dst + base + (size_t)u * ustep) = (unsigned)p;
            }
        }
    }
}

// ---------------- GEMM: 256x256, 8-phase counted-vmcnt (race-fixed schedule) ----------------
// Round-4 bug: ph3/4 (and ph7/8) staged into the buffer being READ in the same
// phase window (A h0 spans ph1 AND ph3 reads since each wave covers a full
// 128-row range). Fixed stage schedule — every target dead at issue:
//   ph1: A1(v)->buf1   [dead since prev ph7]
//   ph2: B0(v)->buf1   [dead since prev ph8]
//   ph3: B1(v)->buf1   [dead since prev ph8]
//   ph4: A0(t2)->buf0  [A h0 dead after ph3]; vmcnt(2) drains tile v, leaves A0(t2)
//   ph5: A1(t2)->buf0  [dead after ph3]
//   ph6: B0(t2)->buf0  [dead after ph4]
//   ph7: B1(t2)->buf0  [dead after ph4]
//   ph8: A0(v+2)->buf1 [A h0 dead after ph7]; vmcnt(2) drains tile t2, leaves A0(v+2)
// In-flight targets never intersect the current phase's read set (checked per phase).
#define BM 256
#define BN 256
#define BKB 128

__global__ __launch_bounds__(512) void gemm_fp8_kernel(
    const unsigned char* __restrict__ Aq,   // [M][K] fp8
    const unsigned char* __restrict__ Bq,   // [N][K] fp8
    const float* __restrict__ bias,
    const unsigned* __restrict__ amax,
    float* __restrict__ out,
    int M, int N, int K) {
    __shared__ alignas(16) unsigned char sA[2][BM * BKB];   // 2 x 32 KB
    __shared__ alignas(16) unsigned char sB[2][BN * BKB];   // 2 x 32 KB

    const int tid = threadIdx.x;
    const int wave = tid >> 6;
    const int lane = tid & 63;
    const int r31 = lane & 31;
    const int half = lane >> 5;
    const int sw = (r31 & 7) << 4;

    int nwg = (int)gridDim.x;
    int bid = (int)blockIdx.x;
    if ((nwg & 7) == 0) {
        int cpx = nwg >> 3;
        bid = (bid & 7) * cpx + (bid >> 3);
    }
    const int nbn = N / BN;
    const int brow = (bid / nbn) * BM;
    const int bcol = (bid % nbn) * BN;

    const int R0 = (wave >> 2) * 128;   // wave row base
    const int C0 = (wave & 3) * 64;     // wave col base

    f32x16 acc[4][2] = {};

    const int NT = K / BKB;
    const int NI = NT / 2;
    const int j0 = tid * 16;

    auto stageA = [&](int buf, int h, int t) {
        #pragma unroll
        for (int j = 0; j < 2; ++j) {
            int oo = j * 8192 + j0;
            int r = oo >> 7;
            int cl = (oo & 127) ^ ((r & 7) << 4);
            g2l16(Aq + (size_t)(brow + h * 128 + r) * K + t * BKB + cl,
                  &sA[buf][h * 16384 + j * 8192 + wave * 1024]);
        }
    };
    auto stageB = [&](int buf, int h, int t) {
        #pragma unroll
        for (int j = 0; j < 2; ++j) {
            int oo = j * 8192 + j0;
            int r = oo >> 7;
            int cl = (oo & 127) ^ ((r & 7) << 4);
            g2l16(Bq + (size_t)(bcol + h * 128 + r) * K + t * BKB + cl,
                  &sB[buf][h * 16384 + j * 8192 + wave * 1024]);
        }
    };
    auto rdA = [&](int buf, int row, int ks) -> i32x8 {
        const unsigned char* base = &sA[buf][row * BKB];
        int kb = ks * 64 + half * 32;
        union { i32x8 v8; i32x4 v4[2]; } u;
        u.v4[0] = *(const i32x4*)(base + (kb ^ sw));
        u.v4[1] = *(const i32x4*)(base + ((kb + 16) ^ sw));
        return u.v8;
    };
    auto rdB = [&](int buf, int row, int ks) -> i32x8 {
        const unsigned char* base = &sB[buf][row * BKB];
        int kb = ks * 64 + half * 32;
        union { i32x8 v8; i32x4 v4[2]; } u;
        u.v4[0] = *(const i32x4*)(base + (kb ^ sw));
        u.v4[1] = *(const i32x4*)(base + ((kb + 16) ^ sw));
        return u.v8;
    };

    #define MM(a, b, c) \
        c = __builtin_amdgcn_mfma_scale_f32_32x32x64_f8f6f4( \
            a, b, c, 0, 0, 0, 0x7f7f7f7f, 0, 0x7f7f7f7f)
    #define BARRIER()  __builtin_amdgcn_s_barrier()
    #define LGKM0()    asm volatile("s_waitcnt lgkmcnt(0)" ::: "memory")
    #define VMCNT2()   asm volatile("s_waitcnt vmcnt(2)" ::: "memory")

    // prologue: tile0 fully + A0(1); keep A0(1) in flight (steady-state carryover)
    stageA(0, 0, 0); stageA(0, 1, 0); stageB(0, 0, 0); stageB(0, 1, 0);
    stageA(1, 0, 1);
    VMCNT2();
    BARRIER();

    for (int I = 0; I < NI; ++I) {
        const int u = 2 * I;
        const int v = u + 1;
        const int t2 = (u + 2 < NT) ? u + 2 : 0;   // dummy reload into dead region on last iter
        const int v2 = (v + 2 < NT) ? v + 2 : 0;

        i32x8 a0[2][2], a1[2][2], b0[2], b1[2];

        // ======== tile u (buf0) ========
        // ph1: m0n0
        #pragma unroll
        for (int f = 0; f < 2; ++f)
            #pragma unroll
            for (int ks = 0; ks < 2; ++ks)
                a0[f][ks] = rdA(0, R0 + f * 32 + r31, ks);
        #pragma unroll
        for (int ks = 0; ks < 2; ++ks) b0[ks] = rdB(0, C0 + r31, ks);
        stageA(1, 1, v);
        BARRIER(); LGKM0();
        __builtin_amdgcn_s_setprio(1);
        #pragma unroll
        for (int f = 0; f < 2; ++f)
            #pragma unroll
            for (int ks = 0; ks < 2; ++ks) MM(a0[f][ks], b0[ks], acc[f][0]);
        __builtin_amdgcn_s_setprio(0);
        BARRIER();

        // ph2: m0n1 (reuse a0)
        #pragma unroll
        for (int ks = 0; ks < 2; ++ks) b1[ks] = rdB(0, C0 + 32 + r31, ks);
        stageB(1, 0, v);
        BARRIER(); LGKM0();
        __builtin_amdgcn_s_setprio(1);
        #pragma unroll
        for (int f = 0; f < 2; ++f)
            #pragma unroll
            for (int ks = 0; ks < 2; ++ks) MM(a0[f][ks], b1[ks], acc[f][1]);
        __builtin_amdgcn_s_setprio(0);
        BARRIER();

        // ph3: m1n1 (reuse b1)
        #pragma unroll
        for (int f = 0; f < 2; ++f)
            #pragma unroll
            for (int ks = 0; ks < 2; ++ks)
                a1[f][ks] = rdA(0, R0 + 64 + f * 32 + r31, ks);
        stageB(1, 1, v);
        BARRIER(); LGKM0();
        __builtin_amdgcn_s_setprio(1);
        #pragma unroll
        for (int f = 0; f < 2; ++f)
            #pragma unroll
            for (int ks = 0; ks < 2; ++ks) MM(a1[f][ks], b1[ks], acc[2 + f][1]);
        __builtin_amdgcn_s_setprio(0);
        BARRIER();

        // ph4: m1n0 (reuse a1; re-read b0); stage A0(t2) into buf0 A h0 (dead after ph3)
        #pragma unroll
        for (int ks = 0; ks < 2; ++ks) b0[ks] = rdB(0, C0 + r31, ks);
        stageA(0, 0, t2);
        VMCNT2();    // drains A1v,B0v,B1v (+prologue/prev A0v already counted) -> tile v landed
        BARRIER(); LGKM0();
        __builtin_amdgcn_s_setprio(1);
        #pragma unroll
        for (int f = 0; f < 2; ++f)
            #pragma unroll
            for (int ks = 0; ks < 2; ++ks) MM(a1[f][ks], b0[ks], acc[2 + f][0]);
        __builtin_amdgcn_s_setprio(0);
        BARRIER();

        // ======== tile v (buf1) ========
        // ph5: m0n0
        #pragma unroll
        for (int f = 0; f < 2; ++f)
            #pragma unroll
            for (int ks = 0; ks < 2; ++ks)
                a0[f][ks] = rdA(1, R0 + f * 32 + r31, ks);
        #pragma unroll
        for (int ks = 0; ks < 2; ++ks) b0[ks] = rdB(1, C0 + r31, ks);
        stageA(0, 1, t2);
        BARRIER(); LGKM0();
        __builtin_amdgcn_s_setprio(1);
        #pragma unroll
        for (int f = 0; f < 2; ++f)
            #pragma unroll
            for (int ks = 0; ks < 2; ++ks) MM(a0[f][ks], b0[ks], acc[f][0]);
        __builtin_amdgcn_s_setprio(0);
        BARRIER();

        // ph6: m0n1
        #pragma unroll
        for (int ks = 0; ks < 2; ++ks) b1[ks] = rdB(1, C0 + 32 + r31, ks);
        stageB(0, 0, t2);
        BARRIER(); LGKM0();
        __builtin_amdgcn_s_setprio(1);
        #pragma unroll
        for (int f = 0; f < 2; ++f)
            #pragma unroll
            for (int ks = 0; ks < 2; ++ks) MM(a0[f][ks], b1[ks], acc[f][1]);
        __builtin_amdgcn_s_setprio(0);
        BARRIER();

        // ph7: m1n1
        #pragma unroll
        for (int f = 0; f < 2; ++f)
            #pragma unroll
            for (int ks = 0; ks < 2; ++ks)
                a1[f][ks] = rdA(1, R0 + 64 + f * 32 + r31, ks);
        stageB(0, 1, t2);
        BARRIER(); LGKM0();
        __builtin_amdgcn_s_setprio(1);
        #pragma unroll
        for (int f = 0; f < 2; ++f)
            #pragma unroll
            for (int ks = 0; ks < 2; ++ks) MM(a1[f][ks], b1[ks], acc[2 + f][1]);
        __builtin_amdgcn_s_setprio(0);
        BARRIER();

        // ph8: m1n0; stage A0(v+2) into buf1 A h0 (dead after ph7)
        #pragma unroll
        for (int ks = 0; ks < 2; ++ks) b0[ks] = rdB(1, C0 + r31, ks);
        stageA(1, 0, v2);
        VMCNT2();    // drains tile t2 -> ready for next iter ph1; leaves A0(v+2)
        BARRIER(); LGKM0();
        __builtin_amdgcn_s_setprio(1);
        #pragma unroll
        for (int f = 0; f < 2; ++f)
            #pragma unroll
            for (int ks = 0; ks < 2; ++ks) MM(a1[f][ks], b0[ks], acc[2 + f][0]);
        __builtin_amdgcn_s_setprio(0);
        BARRIER();
    }

    // epilogue: 32x32 C/D layout: col = lane&31, row = (reg&3) + 8*(reg>>2) + 4*(lane>>5)
    const float invx = 1.0f / scale_from(__uint_as_float(amax[0]));
    const float invw = 1.0f / scale_from(__uint_as_float(amax[1]));
    const float s2 = invx * invw;
    #pragma unroll
    for (int n = 0; n < 2; ++n) {
        int col = bcol + C0 + n * 32 + r31;
        float bv = bias[col];
        #pragma unroll
        for (int m = 0; m < 4; ++m) {
            int rbase = brow + R0 + m * 32 + half * 4;
            #pragma unroll
            for (int r = 0; r < 16; ++r) {
                int row = rbase + (r & 3) + 8 * (r >> 2);
                out[(size_t)row * N + col] = acc[m][n][r] * s2 + bv;
            }
        }
    }
    #undef MM
    #undef BARRIER
    #undef LGKM0
    #undef VMCNT2
}

// ---------------- launch ----------------

extern "C" void kernel_launch(void* const* d_in, const int* in_sizes, int n_in,
                              void* d_out, int out_size, void* d_ws, size_t ws_size,
                              hipStream_t stream) {
    const float* x    = (const float*)d_in[0];
    const float* w    = (const float*)d_in[1];
    const float* bias = (const float*)d_in[2];
    float* out = (float*)d_out;

    const size_t nx = (size_t)in_sizes[0];
    const size_t nw = (size_t)in_sizes[1];
    const int N = in_sizes[2];
    const int K = (int)(nw / (size_t)N);
    const int M = (int)(nx / (size_t)K);

    unsigned* amax = (unsigned*)d_ws;
    unsigned char* xq = (unsigned char*)d_ws + 256;
    unsigned char* wq = xq + nx;

    const int TOTB = 2048;
    int xb = (int)((double)TOTB * (double)nx / (double)(nx + nw));
    if (xb < 1) xb = 1;
    if (xb > TOTB - 1) xb = TOTB - 1;

    init_kernel<<<1, 1, 0, stream>>>(amax);
    amax_fused_kernel<<<TOTB, 256, 0, stream>>>(x, nx, w, nw, amax, xb);
    quant_fused_kernel<<<TOTB, 256, 0, stream>>>(x, nx, w, nw, amax, xq, wq, xb);

    dim3 grid((M / BM) * (N / BN));
    gemm_fp8_kernel<<<grid, 512, 0, stream>>>(xq, wq, bias, amax, out, M, N, K);
}

// Round 6
// 235.957 us; speedup vs baseline: 1.0545x; 1.0545x over previous
//
#include <hip/hip_runtime.h>
#include <hip/hip_bf16.h>

typedef float f32x16 __attribute__((ext_vector_type(16)));
typedef int   i32x8  __attribute__((ext_vector_type(8)));
typedef int   i32x4  __attribute__((ext_vector_type(4)));

#define FP8_MAX 448.0f

// ---------------- helpers ----------------

__device__ __forceinline__ void g2l16(const void* g, void* l) {
    __builtin_amdgcn_global_load_lds(
        (const __attribute__((address_space(1))) void*)g,
        (__attribute__((address_space(3))) void*)l,
        16, 0, 0);
}

__device__ __forceinline__ float scale_from(float amax) {
    float s = FP8_MAX / (amax * 1.1f);
    return (amax == 0.0f) ? 1.0f : fminf(s, 10000.0f);
}

// ---------------- preprocessing (unchanged, verified rounds 3-5) ----------------

__global__ void init_kernel(unsigned* amax) {
    amax[0] = 0u;
    amax[1] = 0u;
}

__global__ void amax_fused_kernel(const float* __restrict__ x, size_t nx,
                                  const float* __restrict__ w, size_t nw,
                                  unsigned* __restrict__ amax, int xblocks) {
    const float* src;
    size_t n;
    unsigned* out;
    int bid, nb;
    if ((int)blockIdx.x < xblocks) {
        src = x; n = nx; out = amax; bid = blockIdx.x; nb = xblocks;
    } else {
        src = w; n = nw; out = amax + 1; bid = blockIdx.x - xblocks; nb = gridDim.x - xblocks;
    }
    float m = 0.0f;
    const size_t ustep = (size_t)blockDim.x * 4;
    const size_t chunkf = ustep * 8;
    size_t base = (size_t)bid * chunkf + (size_t)threadIdx.x * 4;
    const size_t gstride = (size_t)nb * chunkf;
    for (; base < n; base += gstride) {
        float4 v[8];
        #pragma unroll
        for (int u = 0; u < 8; ++u) {
            size_t idx = base + (size_t)u * ustep;
            float4 vv = {0.0f, 0.0f, 0.0f, 0.0f};
            if (idx < n) vv = *(const float4*)(src + idx);
            v[u] = vv;
        }
        #pragma unroll
        for (int u = 0; u < 8; ++u)
            m = fmaxf(m, fmaxf(fmaxf(fabsf(v[u].x), fabsf(v[u].y)),
                               fmaxf(fabsf(v[u].z), fabsf(v[u].w))));
    }
    #pragma unroll
    for (int off = 32; off > 0; off >>= 1)
        m = fmaxf(m, __shfl_xor(m, off));
    __shared__ float sm[4];
    if ((threadIdx.x & 63) == 0) sm[threadIdx.x >> 6] = m;
    __syncthreads();
    if (threadIdx.x == 0) {
        float mm = fmaxf(fmaxf(sm[0], sm[1]), fmaxf(sm[2], sm[3]));
        atomicMax(out, __float_as_uint(mm));
    }
}

__device__ __forceinline__ float qclamp(float v, float s) {
    return fminf(fmaxf(v * s, -FP8_MAX), FP8_MAX);
}

__global__ void quant_fused_kernel(const float* __restrict__ x, size_t nx,
                                   const float* __restrict__ w, size_t nw,
                                   const unsigned* __restrict__ amax,
                                   unsigned char* __restrict__ xq,
                                   unsigned char* __restrict__ wq, int xblocks) {
    const float* src;
    size_t n;
    unsigned char* dst;
    int bid, nb, sel;
    if ((int)blockIdx.x < xblocks) {
        src = x; n = nx; dst = xq; bid = blockIdx.x; nb = xblocks; sel = 0;
    } else {
        src = w; n = nw; dst = wq; bid = blockIdx.x - xblocks; nb = gridDim.x - xblocks; sel = 1;
    }
    const float s = scale_from(__uint_as_float(amax[sel]));
    const size_t ustep = (size_t)blockDim.x * 4;
    const size_t chunkf = ustep * 4;
    size_t base = (size_t)bid * chunkf + (size_t)threadIdx.x * 4;
    const size_t gstride = (size_t)nb * chunkf;
    for (; base < n; base += gstride) {
        float4 v[4];
        bool ok[4];
        #pragma unroll
        for (int u = 0; u < 4; ++u) {
            size_t idx = base + (size_t)u * ustep;
            ok[u] = idx < n;
            float4 vv = {0.0f, 0.0f, 0.0f, 0.0f};
            if (ok[u]) vv = *(const float4*)(src + idx);
            v[u] = vv;
        }
        #pragma unroll
        for (int u = 0; u < 4; ++u) {
            if (ok[u]) {
                int p = __builtin_amdgcn_cvt_pk_fp8_f32(qclamp(v[u].x, s), qclamp(v[u].y, s), 0, false);
                p = __builtin_amdgcn_cvt_pk_fp8_f32(qclamp(v[u].z, s), qclamp(v[u].w, s), p, true);
                *(unsigned*)(dst + base + (size_t)u * ustep) = (unsigned)p;
            }
        }
    }
}

// ---------------- GEMM: 256x256 tile, ring-4 K-tile pipeline, counted vmcnt ----------------
// Round-5 lesson: with 2 LDS buffers x 4-phase windows, a stage target is dead
// for <=1 phase before its drain -> ~700cyc cover for ~900cyc latency-bound
// loads -> stall (MfmaUtil 32%). Fix: ring of 4 FULL K-tiles (BKB=64B, 32KB
// each, 128KiB LDS). Per iter (1 K-tile): ds_read frags(t) | stage tile t+3
// into slot (t+3)&3 (held t-1, dead since last iter's 2nd barrier) | vmcnt(8)
// (drains t+1: issued 2 full iterations earlier; leaves t+2,t+3 in flight) |
// barrier | lgkm0 | 8x mfma_scale (independent accs) | barrier.
// Liveness: reads of tile t occur iter t only; slot (t+3)&3 last read iter t-1
// before its 2nd barrier; stage issue follows that barrier. Drain: tile j
// forced complete at iter j-1's vmcnt(8), all-wave-synced at the next barrier.
// Swizzle (64B rows): 16B chunk c of row r stored at c ^ ((r>>1)&3) -> over 8
// rows covers all 8 bank-groups (4 lanes/group = conflict-free minimum).
#define BM 256
#define BN 256
#define BKB 64

__global__ __launch_bounds__(512, 2) void gemm_fp8_kernel(
    const unsigned char* __restrict__ Aq,   // [M][K] fp8
    const unsigned char* __restrict__ Bq,   // [N][K] fp8
    const float* __restrict__ bias,
    const unsigned* __restrict__ amax,
    float* __restrict__ out,
    int M, int N, int K) {
    __shared__ alignas(16) unsigned char sA[4][BM * BKB];   // 4 x 16 KB
    __shared__ alignas(16) unsigned char sB[4][BN * BKB];   // 4 x 16 KB

    const int tid = threadIdx.x;
    const int wave = tid >> 6;
    const int lane = tid & 63;
    const int r31 = lane & 31;
    const int half = lane >> 5;

    int nwg = (int)gridDim.x;
    int bid = (int)blockIdx.x;
    if ((nwg & 7) == 0) {
        int cpx = nwg >> 3;
        bid = (bid & 7) * cpx + (bid >> 3);
    }
    const int nbn = N / BN;
    const int brow = (bid / nbn) * BM;
    const int bcol = (bid % nbn) * BN;

    const int R0 = (wave >> 2) * 128;   // wave row base (2M)
    const int C0 = (wave & 3) * 64;     // wave col base (4N)

    f32x16 acc[4][2] = {};

    const int NT = K / BKB;             // 64 (NT%4==0 for these dims)
    const int j0 = tid * 16;

    auto stageA = [&](int slot, int t) {
        #pragma unroll
        for (int j = 0; j < 2; ++j) {
            int oo = j * 8192 + j0;
            int r = oo >> 6;                              // row 0..255
            int c = (oo & 63) ^ (((r >> 1) & 3) << 4);    // pre-swizzled source col
            g2l16(Aq + (size_t)(brow + r) * K + t * BKB + c,
                  &sA[slot][j * 8192 + wave * 1024]);
        }
    };
    auto stageB = [&](int slot, int t) {
        #pragma unroll
        for (int j = 0; j < 2; ++j) {
            int oo = j * 8192 + j0;
            int r = oo >> 6;
            int c = (oo & 63) ^ (((r >> 1) & 3) << 4);
            g2l16(Bq + (size_t)(bcol + r) * K + t * BKB + c,
                  &sB[slot][j * 8192 + wave * 1024]);
        }
    };
    auto rdA = [&](int slot, int row) -> i32x8 {
        const unsigned char* base = &sA[slot][row * BKB];
        int swz = ((row >> 1) & 3) << 4;
        int kb = half * 32;
        union { i32x8 v8; i32x4 v4[2]; } u;
        u.v4[0] = *(const i32x4*)(base + (kb ^ swz));
        u.v4[1] = *(const i32x4*)(base + ((kb + 16) ^ swz));
        return u.v8;
    };
    auto rdB = [&](int slot, int row) -> i32x8 {
        const unsigned char* base = &sB[slot][row * BKB];
        int swz = ((row >> 1) & 3) << 4;
        int kb = half * 32;
        union { i32x8 v8; i32x4 v4[2]; } u;
        u.v4[0] = *(const i32x4*)(base + (kb ^ swz));
        u.v4[1] = *(const i32x4*)(base + ((kb + 16) ^ swz));
        return u.v8;
    };

    #define MM(a, b, c) \
        c = __builtin_amdgcn_mfma_scale_f32_32x32x64_f8f6f4( \
            a, b, c, 0, 0, 0, 0x7f7f7f7f, 0, 0x7f7f7f7f)

    // prologue: stage tiles 0,1,2; drain tile 0 (vmcnt(8) leaves t1,t2); sync
    stageA(0, 0); stageB(0, 0);
    stageA(1, 1); stageB(1, 1);
    stageA(2, 2); stageB(2, 2);
    asm volatile("s_waitcnt vmcnt(8)" ::: "memory");
    __builtin_amdgcn_s_barrier();

    for (int t = 0; t < NT; ++t) {
        const int s = t & 3;
        i32x8 a[4], b[2];
        #pragma unroll
        for (int m = 0; m < 4; ++m) a[m] = rdA(s, R0 + m * 32 + r31);
        #pragma unroll
        for (int n = 0; n < 2; ++n) b[n] = rdB(s, C0 + n * 32 + r31);

        int tt = t + 3;
        if (tt >= NT) tt -= NT;          // dummy re-stage into never-again-read slot
        stageA(tt & 3, tt);
        stageB(tt & 3, tt);

        asm volatile("s_waitcnt vmcnt(8)" ::: "memory");   // drain tile t+1; keep t+2,t+3 in flight
        __builtin_amdgcn_s_barrier();
        asm volatile("s_waitcnt lgkmcnt(0)" ::: "memory");
        __builtin_amdgcn_sched_barrier(0);                 // rule #18: pin MFMA below lgkm wait

        __builtin_amdgcn_s_setprio(1);
        #pragma unroll
        for (int m = 0; m < 4; ++m)
            #pragma unroll
            for (int n = 0; n < 2; ++n)
                MM(a[m], b[n], acc[m][n]);
        __builtin_amdgcn_s_setprio(0);
        __builtin_amdgcn_s_barrier();
    }

    // epilogue: 32x32 C/D layout: col = lane&31, row = (reg&3) + 8*(reg>>2) + 4*(lane>>5)
    const float invx = 1.0f / scale_from(__uint_as_float(amax[0]));
    const float invw = 1.0f / scale_from(__uint_as_float(amax[1]));
    const float s2 = invx * invw;
    #pragma unroll
    for (int n = 0; n < 2; ++n) {
        int col = bcol + C0 + n * 32 + r31;
        float bv = bias[col];
        #pragma unroll
        for (int m = 0; m < 4; ++m) {
            int rbase = brow + R0 + m * 32 + half * 4;
            #pragma unroll
            for (int r = 0; r < 16; ++r) {
                int row = rbase + (r & 3) + 8 * (r >> 2);
                out[(size_t)row * N + col] = acc[m][n][r] * s2 + bv;
            }
        }
    }
    #undef MM
}

// ---------------- launch ----------------

extern "C" void kernel_launch(void* const* d_in, const int* in_sizes, int n_in,
                              void* d_out, int out_size, void* d_ws, size_t ws_size,
                              hipStream_t stream) {
    const float* x    = (const float*)d_in[0];
    const float* w    = (const float*)d_in[1];
    const float* bias = (const float*)d_in[2];
    float* out = (float*)d_out;

    const size_t nx = (size_t)in_sizes[0];
    const size_t nw = (size_t)in_sizes[1];
    const int N = in_sizes[2];
    const int K = (int)(nw / (size_t)N);
    const int M = (int)(nx / (size_t)K);

    unsigned* amax = (unsigned*)d_ws;
    unsigned char* xq = (unsigned char*)d_ws + 256;
    unsigned char* wq = xq + nx;

    const int TOTB = 2048;
    int xb = (int)((double)TOTB * (double)nx / (double)(nx + nw));
    if (xb < 1) xb = 1;
    if (xb > TOTB - 1) xb = TOTB - 1;

    init_kernel<<<1, 1, 0, stream>>>(amax);
    amax_fused_kernel<<<TOTB, 256, 0, stream>>>(x, nx, w, nw, amax, xb);
    quant_fused_kernel<<<TOTB, 256, 0, stream>>>(x, nx, w, nw, amax, xq, wq, xb);

    dim3 grid((M / BM) * (N / BN));
    gemm_fp8_kernel<<<grid, 512, 0, stream>>>(xq, wq, bias, amax, out, M, N, K);
}

// Round 7
// 231.696 us; speedup vs baseline: 1.0739x; 1.0184x over previous
//
#include <hip/hip_runtime.h>
#include <hip/hip_bf16.h>

typedef float f32x16 __attribute__((ext_vector_type(16)));
typedef int   i32x8  __attribute__((ext_vector_type(8)));
typedef int   i32x4  __attribute__((ext_vector_type(4)));

#define FP8_MAX 448.0f

// ---------------- helpers ----------------

__device__ __forceinline__ void g2l16(const void* g, void* l) {
    __builtin_amdgcn_global_load_lds(
        (const __attribute__((address_space(1))) void*)g,
        (__attribute__((address_space(3))) void*)l,
        16, 0, 0);
}

__device__ __forceinline__ float scale_from(float amax) {
    float s = FP8_MAX / (amax * 1.1f);
    return (amax == 0.0f) ? 1.0f : fminf(s, 10000.0f);
}

// ---------------- preprocessing (unchanged; measured at its BW roofline) ----------------

__global__ void init_kernel(unsigned* amax) {
    amax[0] = 0u;
    amax[1] = 0u;
}

__global__ void amax_fused_kernel(const float* __restrict__ x, size_t nx,
                                  const float* __restrict__ w, size_t nw,
                                  unsigned* __restrict__ amax, int xblocks) {
    const float* src;
    size_t n;
    unsigned* out;
    int bid, nb;
    if ((int)blockIdx.x < xblocks) {
        src = x; n = nx; out = amax; bid = blockIdx.x; nb = xblocks;
    } else {
        src = w; n = nw; out = amax + 1; bid = blockIdx.x - xblocks; nb = gridDim.x - xblocks;
    }
    float m = 0.0f;
    const size_t ustep = (size_t)blockDim.x * 4;
    const size_t chunkf = ustep * 8;
    size_t base = (size_t)bid * chunkf + (size_t)threadIdx.x * 4;
    const size_t gstride = (size_t)nb * chunkf;
    for (; base < n; base += gstride) {
        float4 v[8];
        #pragma unroll
        for (int u = 0; u < 8; ++u) {
            size_t idx = base + (size_t)u * ustep;
            float4 vv = {0.0f, 0.0f, 0.0f, 0.0f};
            if (idx < n) vv = *(const float4*)(src + idx);
            v[u] = vv;
        }
        #pragma unroll
        for (int u = 0; u < 8; ++u)
            m = fmaxf(m, fmaxf(fmaxf(fabsf(v[u].x), fabsf(v[u].y)),
                               fmaxf(fabsf(v[u].z), fabsf(v[u].w))));
    }
    #pragma unroll
    for (int off = 32; off > 0; off >>= 1)
        m = fmaxf(m, __shfl_xor(m, off));
    __shared__ float sm[4];
    if ((threadIdx.x & 63) == 0) sm[threadIdx.x >> 6] = m;
    __syncthreads();
    if (threadIdx.x == 0) {
        float mm = fmaxf(fmaxf(sm[0], sm[1]), fmaxf(sm[2], sm[3]));
        atomicMax(out, __float_as_uint(mm));
    }
}

__device__ __forceinline__ float qclamp(float v, float s) {
    return fminf(fmaxf(v * s, -FP8_MAX), FP8_MAX);
}

__global__ void quant_fused_kernel(const float* __restrict__ x, size_t nx,
                                   const float* __restrict__ w, size_t nw,
                                   const unsigned* __restrict__ amax,
                                   unsigned char* __restrict__ xq,
                                   unsigned char* __restrict__ wq, int xblocks) {
    const float* src;
    size_t n;
    unsigned char* dst;
    int bid, nb, sel;
    if ((int)blockIdx.x < xblocks) {
        src = x; n = nx; dst = xq; bid = blockIdx.x; nb = xblocks; sel = 0;
    } else {
        src = w; n = nw; dst = wq; bid = blockIdx.x - xblocks; nb = gridDim.x - xblocks; sel = 1;
    }
    const float s = scale_from(__uint_as_float(amax[sel]));
    const size_t ustep = (size_t)blockDim.x * 4;
    const size_t chunkf = ustep * 4;
    size_t base = (size_t)bid * chunkf + (size_t)threadIdx.x * 4;
    const size_t gstride = (size_t)nb * chunkf;
    for (; base < n; base += gstride) {
        float4 v[4];
        bool ok[4];
        #pragma unroll
        for (int u = 0; u < 4; ++u) {
            size_t idx = base + (size_t)u * ustep;
            ok[u] = idx < n;
            float4 vv = {0.0f, 0.0f, 0.0f, 0.0f};
            if (ok[u]) vv = *(const float4*)(src + idx);
            v[u] = vv;
        }
        #pragma unroll
        for (int u = 0; u < 4; ++u) {
            if (ok[u]) {
                int p = __builtin_amdgcn_cvt_pk_fp8_f32(qclamp(v[u].x, s), qclamp(v[u].y, s), 0, false);
                p = __builtin_amdgcn_cvt_pk_fp8_f32(qclamp(v[u].z, s), qclamp(v[u].w, s), p, true);
                *(unsigned*)(dst + base + (size_t)u * ustep) = (unsigned)p;
            }
        }
    }
}

// ---------------- GEMM: ring-4 + register double-buffer, MFMA||ds_read overlap --------
// Round-6 lesson: barrier-phased {reads | MFMA} alternates the LDS and MFMA
// pipes CU-wide (measured 3094 cyc/K-iter vs 1100 MFMA need). Fix: read tile
// t+1's fragments into the OTHER regset, then run tile t's MFMAs — the 12
// ds_read_b128 retire on the LDS pipe underneath the MFMAs; consumed next
// half-step. One barrier per K-tile, preceded by s_waitcnt vmcnt(8) lgkmcnt(0):
//   vmcnt(8): stages outstanding = t+1,t+2,t+3 (4 each) -> drains t+1 (issued
//             3 half-steps earlier, ~3000cyc cover >> ~900cyc HBM latency);
//   lgkmcnt(0): my reads of t-1 COMPLETE before anyone stages into its slot
//             (slot (t+3)&3 holds t-1; stage is issued right after this barrier
//             on the fastest wave).
// Unroll x4 => all slot indices compile-time (rule #20), regsets A/B alternate.
// sched_barrier(0) pins: reads below the barrier, MFMAs below the reads.
#define BM 256
#define BN 256
#define BKB 64

__global__ __launch_bounds__(512, 2) void gemm_fp8_kernel(
    const unsigned char* __restrict__ Aq,   // [M][K] fp8
    const unsigned char* __restrict__ Bq,   // [N][K] fp8
    const float* __restrict__ bias,
    const unsigned* __restrict__ amax,
    float* __restrict__ out,
    int M, int N, int K) {
    __shared__ alignas(16) unsigned char sA[4][BM * BKB];   // 4 x 16 KB
    __shared__ alignas(16) unsigned char sB[4][BN * BKB];   // 4 x 16 KB

    const int tid = threadIdx.x;
    const int wave = tid >> 6;
    const int lane = tid & 63;
    const int r31 = lane & 31;
    const int half = lane >> 5;

    int nwg = (int)gridDim.x;
    int bid = (int)blockIdx.x;
    if ((nwg & 7) == 0) {
        int cpx = nwg >> 3;
        bid = (bid & 7) * cpx + (bid >> 3);
    }
    const int nbn = N / BN;
    const int brow = (bid / nbn) * BM;
    const int bcol = (bid % nbn) * BN;

    const int R0 = (wave >> 2) * 128;   // wave row base (2M)
    const int C0 = (wave & 3) * 64;     // wave col base (4N)

    f32x16 acc[4][2] = {};

    const int NT = K / BKB;             // 64
    const int j0 = tid * 16;

    auto stageA = [&](int slot, int t) {
        #pragma unroll
        for (int j = 0; j < 2; ++j) {
            int oo = j * 8192 + j0;
            int r = oo >> 6;
            int c = (oo & 63) ^ (((r >> 1) & 3) << 4);    // pre-swizzled source col
            g2l16(Aq + (size_t)(brow + r) * K + t * BKB + c,
                  &sA[slot][j * 8192 + wave * 1024]);
        }
    };
    auto stageB = [&](int slot, int t) {
        #pragma unroll
        for (int j = 0; j < 2; ++j) {
            int oo = j * 8192 + j0;
            int r = oo >> 6;
            int c = (oo & 63) ^ (((r >> 1) & 3) << 4);
            g2l16(Bq + (size_t)(bcol + r) * K + t * BKB + c,
                  &sB[slot][j * 8192 + wave * 1024]);
        }
    };
    auto rdA = [&](int slot, int row) -> i32x8 {
        const unsigned char* base = &sA[slot][row * BKB];
        int swz = ((row >> 1) & 3) << 4;
        int kb = half * 32;
        union { i32x8 v8; i32x4 v4[2]; } u;
        u.v4[0] = *(const i32x4*)(base + (kb ^ swz));
        u.v4[1] = *(const i32x4*)(base + ((kb + 16) ^ swz));
        return u.v8;
    };
    auto rdB = [&](int slot, int row) -> i32x8 {
        const unsigned char* base = &sB[slot][row * BKB];
        int swz = ((row >> 1) & 3) << 4;
        int kb = half * 32;
        union { i32x8 v8; i32x4 v4[2]; } u;
        u.v4[0] = *(const i32x4*)(base + (kb ^ swz));
        u.v4[1] = *(const i32x4*)(base + ((kb + 16) ^ swz));
        return u.v8;
    };

    #define MM(a, b, c) \
        c = __builtin_amdgcn_mfma_scale_f32_32x32x64_f8f6f4( \
            a, b, c, 0, 0, 0, 0x7f7f7f7f, 0, 0x7f7f7f7f)

    i32x8 aA[4], bA[2], aB[4], bB[2];   // two statically-named regsets

    // prologue: stage tiles 0,1,2 (12 outstanding); drain tile0; read tile0 -> set A
    stageA(0, 0); stageB(0, 0);
    stageA(1, 1); stageB(1, 1);
    stageA(2, 2); stageB(2, 2);
    asm volatile("s_waitcnt vmcnt(8)" ::: "memory");
    __builtin_amdgcn_s_barrier();
    __builtin_amdgcn_sched_barrier(0);
    #pragma unroll
    for (int m = 0; m < 4; ++m) aA[m] = rdA(0, R0 + m * 32 + r31);
    #pragma unroll
    for (int n = 0; n < 2; ++n) bA[n] = rdB(0, C0 + n * 32 + r31);

    // HALF(j): compute tile t=tb+j from CUR; read tile t+1 (slot (j+1)&3) into NXT;
    //          stage tile t+3 (slot (j+3)&3).
    #define HALF(j, CURa, CURb, NXTa, NXTb)                                       \
    {                                                                             \
        int t = tb + (j);                                                         \
        int ts = t + 3;                                                           \
        if (ts >= NT) ts -= NT;          /* dummy re-stage into dead slot */      \
        stageA(((j) + 3) & 3, ts);                                                \
        stageB(((j) + 3) & 3, ts);                                                \
        asm volatile("s_waitcnt vmcnt(8) lgkmcnt(0)" ::: "memory");               \
        __builtin_amdgcn_s_barrier();                                             \
        __builtin_amdgcn_sched_barrier(0);                                        \
        _Pragma("unroll")                                                         \
        for (int m = 0; m < 4; ++m) NXTa[m] = rdA(((j) + 1) & 3, R0 + m * 32 + r31); \
        _Pragma("unroll")                                                         \
        for (int n = 0; n < 2; ++n) NXTb[n] = rdB(((j) + 1) & 3, C0 + n * 32 + r31); \
        __builtin_amdgcn_sched_barrier(0);   /* keep reads issued before MFMAs */ \
        __builtin_amdgcn_s_setprio(1);                                            \
        _Pragma("unroll")                                                         \
        for (int m = 0; m < 4; ++m)                                               \
            _Pragma("unroll")                                                     \
            for (int n = 0; n < 2; ++n)                                           \
                MM(CURa[m], CURb[n], acc[m][n]);                                  \
        __builtin_amdgcn_s_setprio(0);                                            \
    }

    for (int tb = 0; tb < NT; tb += 4) {
        HALF(0, aA, bA, aB, bB)
        HALF(1, aB, bB, aA, bA)
        HALF(2, aA, bA, aB, bB)
        HALF(3, aB, bB, aA, bA)
    }
    #undef HALF

    // epilogue: 32x32 C/D layout: col = lane&31, row = (reg&3) + 8*(reg>>2) + 4*(lane>>5)
    const float invx = 1.0f / scale_from(__uint_as_float(amax[0]));
    const float invw = 1.0f / scale_from(__uint_as_float(amax[1]));
    const float s2 = invx * invw;
    #pragma unroll
    for (int n = 0; n < 2; ++n) {
        int col = bcol + C0 + n * 32 + r31;
        float bv = bias[col];
        #pragma unroll
        for (int m = 0; m < 4; ++m) {
            int rbase = brow + R0 + m * 32 + half * 4;
            #pragma unroll
            for (int r = 0; r < 16; ++r) {
                int row = rbase + (r & 3) + 8 * (r >> 2);
                out[(size_t)row * N + col] = acc[m][n][r] * s2 + bv;
            }
        }
    }
    #undef MM
}

// ---------------- launch ----------------

extern "C" void kernel_launch(void* const* d_in, const int* in_sizes, int n_in,
                              void* d_out, int out_size, void* d_ws, size_t ws_size,
                              hipStream_t stream) {
    const float* x    = (const float*)d_in[0];
    const float* w    = (const float*)d_in[1];
    const float* bias = (const float*)d_in[2];
    float* out = (float*)d_out;

    const size_t nx = (size_t)in_sizes[0];
    const size_t nw = (size_t)in_sizes[1];
    const int N = in_sizes[2];
    const int K = (int)(nw / (size_t)N);
    const int M = (int)(nx / (size_t)K);

    unsigned* amax = (unsigned*)d_ws;
    unsigned char* xq = (unsigned char*)d_ws + 256;
    unsigned char* wq = xq + nx;

    const int TOTB = 2048;
    int xb = (int)((double)TOTB * (double)nx / (double)(nx + nw));
    if (xb < 1) xb = 1;
    if (xb > TOTB - 1) xb = TOTB - 1;

    init_kernel<<<1, 1, 0, stream>>>(amax);
    amax_fused_kernel<<<TOTB, 256, 0, stream>>>(x, nx, w, nw, amax, xb);
    quant_fused_kernel<<<TOTB, 256, 0, stream>>>(x, nx, w, nw, amax, xq, wq, xb);

    dim3 grid((M / BM) * (N / BN));
    gemm_fp8_kernel<<<grid, 512, 0, stream>>>(xq, wq, bias, amax, out, M, N, K);
}